// Round 2
// 606.796 us; speedup vs baseline: 1.1026x; 1.1026x over previous
//
#include <hip/hip_runtime.h>
#include <stdint.h>

#define EPSF 1e-7f
#define MAXTAN 10.0f

typedef __bf16 bf16x8 __attribute__((ext_vector_type(8)));
typedef float floatx4 __attribute__((ext_vector_type(4)));
typedef __attribute__((address_space(3))) void lds_void_t;
typedef __attribute__((address_space(1))) void gbl_void_t;

__device__ __forceinline__ unsigned short f2bf(float x) {
  union { float f; uint32_t u; } v; v.f = x;
  uint32_t u = v.u;
  u += 0x7fffu + ((u >> 16) & 1u);   // RNE
  return (unsigned short)(u >> 16);
}
__device__ __forceinline__ float bf2f(unsigned short h) {
  union { uint32_t u; float f; } v; v.u = ((uint32_t)h) << 16;
  return v.f;
}

__device__ __forceinline__ int sniff_mode(const unsigned short* x) {
  int sane = 0;
  for (int i = 0; i < 128; ++i) {
    unsigned short h = x[i];
    int e = (h >> 7) & 0xFF;
    if ((h & 0x7FFF) == 0 || (e >= 96 && e <= 140)) ++sane;
  }
  return (sane >= 120) ? 1 : 0;
}

// ---------------- init: sniff dtype + convert biases ----------------
__global__ void k_init(const unsigned short* __restrict__ x, int* __restrict__ modeg,
                       const void* __restrict__ b1, const void* __restrict__ b2,
                       const void* __restrict__ b3, float* __restrict__ o1,
                       float* __restrict__ o2, float* __restrict__ o3) {
  __shared__ int mds;
  if (threadIdx.x == 0) {
    int m = sniff_mode(x);
    mds = m;
    if (blockIdx.x == 0) *modeg = m;
  }
  __syncthreads();
  int m = mds;
  int i = blockIdx.x * 256 + threadIdx.x;
  if (i < 4096) o1[i] = m ? bf2f(((const unsigned short*)b1)[i]) : ((const float*)b1)[i];
  if (i < 4096) o2[i] = m ? bf2f(((const unsigned short*)b2)[i]) : ((const float*)b2)[i];
  if (i < 1024) o3[i] = m ? bf2f(((const unsigned short*)b3)[i]) : ((const float*)b3)[i];
}

// ---------------- x prep: convert to bf16, compute logmap scale + x0 ----------------
__global__ void k_prep(const void* __restrict__ xv, unsigned short* __restrict__ xb,
                       float* __restrict__ sc0, float* __restrict__ x0c,
                       const int* __restrict__ mode) {
  const int row = blockIdx.x;
  const int tid = threadIdx.x;
  float4 v;
  if (*mode) {
    ushort4 u = ((const ushort4*)((const unsigned short*)xv + (size_t)row * 1024))[tid];
    v.x = bf2f(u.x); v.y = bf2f(u.y); v.z = bf2f(u.z); v.w = bf2f(u.w);
  } else {
    v = ((const float4*)((const float*)xv + (size_t)row * 1024))[tid];
  }
  ushort4 o;
  o.x = f2bf(v.x); o.y = f2bf(v.y); o.z = f2bf(v.z); o.w = f2bf(v.w);
  ((ushort4*)(xb + (size_t)row * 1024))[tid] = o;

  float s = v.x * v.x + v.y * v.y + v.z * v.z + v.w * v.w;
  if (tid == 0) s -= v.x * v.x;          // exclude time coordinate
  for (int off = 32; off; off >>= 1) s += __shfl_down(s, off, 64);
  __shared__ float red[4];
  if ((tid & 63) == 0) red[tid >> 6] = s;
  __syncthreads();
  if (tid == 0) {
    s = red[0] + red[1] + red[2] + red[3];
    float ns = fmaxf(sqrtf(s), EPSF);
    float d = acoshf(fmaxf(v.x, 1.0f + EPSF));
    sc0[row] = d / ns;
    x0c[row] = bf2f(o.x);
  }
}

// ---------------- weight convert to bf16 + col0 extraction ----------------
template<int K8>
__global__ void k_cvtw(const void* __restrict__ in, unsigned short* __restrict__ out,
                       const int* __restrict__ mode, int n8, float* __restrict__ c0) {
  int i = blockIdx.x * 256 + threadIdx.x;
  if (i >= n8) return;
  if (*mode) {
    uint4 g = ((const uint4*)in)[i];
    ((uint4*)out)[i] = g;
    if (i % K8 == 0) c0[i / K8] = bf2f((unsigned short)(g.x & 0xFFFFu));
  } else {
    float4 a = ((const float4*)in)[2 * i];
    float4 b = ((const float4*)in)[2 * i + 1];
    ushort4 oa, ob;
    oa.x = f2bf(a.x); oa.y = f2bf(a.y); oa.z = f2bf(a.z); oa.w = f2bf(a.w);
    ob.x = f2bf(b.x); ob.y = f2bf(b.y); ob.z = f2bf(b.z); ob.w = f2bf(b.w);
    ((ushort4*)out)[2 * i] = oa;
    ((ushort4*)out)[2 * i + 1] = ob;
    if (i % K8 == 0) c0[i / K8] = bf2f(oa.x);
  }
}

// ---------------- partial-sumsq fold -> scale + col0 grab ----------------
template<int NBLK>
__global__ void k_sc(const float* __restrict__ part, const unsigned short* __restrict__ y,
                     int stride, float* __restrict__ sc, float* __restrict__ c0,
                     float* __restrict__ ssout, int nrows) {
  int i = blockIdx.x * 256 + threadIdx.x;
  if (i >= nrows) return;
  float s = 0.f;
#pragma unroll
  for (int j = 0; j < NBLK; ++j) s += part[(size_t)i * NBLK + j];
  float n = fmaxf(sqrtf(fmaxf(s, 0.f)), EPSF);
  sc[i] = fminf(n, MAXTAN) / n;
  c0[i] = bf2f(y[(size_t)i * stride]);
  if (ssout) ssout[i] = s;
}

// ---------------- final: y3 bf16 + ss3 -> projx(safe_expmap0(y3)) ----------------
__global__ void k_final(const unsigned short* __restrict__ y, const float* __restrict__ ss,
                        void* __restrict__ outv, const int* __restrict__ mode) {
  const int row = blockIdx.x;
  const int tid = threadIdx.x;
  float n = fmaxf(sqrtf(fmaxf(ss[row], 0.f)), EPSF);
  float nc = fminf(n, MAXTAN);
  float a = sinhf(nc) / n;
  ushort4 u = ((const ushort4*)(y + (size_t)row * 1024))[tid];
  float4 o;
  o.x = bf2f(u.x) * a; o.y = bf2f(u.y) * a;
  o.z = bf2f(u.z) * a; o.w = bf2f(u.w) * a;
  if (tid == 0) o.x = coshf(nc);
  if (*mode) {
    ushort4 o16;
    o16.x = f2bf(o.x); o16.y = f2bf(o.y); o16.z = f2bf(o.z); o16.w = f2bf(o.w);
    ((ushort4*)outv)[(size_t)row * 256 + tid] = o16;
  } else {
    ((float4*)outv)[(size_t)row * 256 + tid] = o;
  }
}

// ---------------- legacy 128x128 NT GEMM (kept for GEMM3: N=1024 grid too small for 256^2) ----------------
template<int N, int K, int NBLK, int GX>
__global__ __launch_bounds__(256, 4) void k_gemm_bt(
    const unsigned short* __restrict__ A,
    const unsigned short* __restrict__ B,
    const float* __restrict__ bias,
    const float* __restrict__ sc,
    const float* __restrict__ c0f,
    const float* __restrict__ wc0,
    unsigned short* __restrict__ Cb,
    float* __restrict__ part)
{
  __shared__ __align__(16) unsigned short As[128 * 32];
  __shared__ __align__(16) unsigned short Bs[128 * 32];

  const int tid  = threadIdx.x;
  const int wave = tid >> 6;
  const int lane = tid & 63;
  const int quad = lane >> 4;
  const int m16  = lane & 15;

  const int j = blockIdx.x & 7;
  const int k = blockIdx.x >> 3;
  int bxi, byi;
  if (GX == 32) {
    bxi = 16 * (j & 1) + (k & 15);
    byi = 16 * (j >> 1) + (k >> 4);
  } else {
    bxi = k & 7;
    byi = 8 * j + (k >> 3);
  }
  const int bm = byi * 128;
  const int bn = bxi * 128;

  const int srow = lane >> 2;
  const int scol = (((lane & 3) ^ ((srow >> 1) & 3)) << 3);

  const int wm = (wave >> 1) << 6;
  const int wn = (wave & 1) << 6;

  const int rsw = ((quad ^ ((m16 >> 1) & 3)) << 3);

  const int c0i = wave * 2;
  const unsigned short* ga0 = A + (size_t)(bm + c0i * 16 + srow) * K + scol;
  const unsigned short* ga1 = ga0 + (size_t)16 * K;
  const unsigned short* gb0 = B + (size_t)(bn + c0i * 16 + srow) * K + scol;
  const unsigned short* gb1 = gb0 + (size_t)16 * K;

  floatx4 acc[4][4];
#pragma unroll
  for (int i = 0; i < 4; ++i)
#pragma unroll
    for (int jj = 0; jj < 4; ++jj)
#pragma unroll
      for (int r = 0; r < 4; ++r) acc[i][jj][r] = 0.0f;

  for (int k0 = 0; k0 < K; k0 += 32) {
    __builtin_amdgcn_global_load_lds((gbl_void_t*)(void*)ga0,
                                     (lds_void_t*)(As + c0i * 512), 16, 0, 0);
    __builtin_amdgcn_global_load_lds((gbl_void_t*)(void*)ga1,
                                     (lds_void_t*)(As + c0i * 512 + 512), 16, 0, 0);
    __builtin_amdgcn_global_load_lds((gbl_void_t*)(void*)gb0,
                                     (lds_void_t*)(Bs + c0i * 512), 16, 0, 0);
    __builtin_amdgcn_global_load_lds((gbl_void_t*)(void*)gb1,
                                     (lds_void_t*)(Bs + c0i * 512 + 512), 16, 0, 0);
    ga0 += 32; ga1 += 32; gb0 += 32; gb1 += 32;
    __syncthreads();

    bf16x8 af[4], bfg[4];
#pragma unroll
    for (int t = 0; t < 4; ++t) {
      af[t]  = *(const bf16x8*)(As + (wm + t * 16 + m16) * 32 + rsw);
      bfg[t] = *(const bf16x8*)(Bs + (wn + t * 16 + m16) * 32 + rsw);
    }
#pragma unroll
    for (int mt = 0; mt < 4; ++mt)
#pragma unroll
      for (int nt = 0; nt < 4; ++nt)
        acc[mt][nt] = __builtin_amdgcn_mfma_f32_16x16x32_bf16(af[mt], bfg[nt], acc[mt][nt], 0, 0, 0);
    __syncthreads();
  }

#pragma unroll
  for (int mt = 0; mt < 4; ++mt) {
#pragma unroll
    for (int r = 0; r < 4; ++r) {
      const int gm = bm + wm + mt * 16 + quad * 4 + r;
      const float scv = sc[gm];
      const float c0v = c0f[gm];
      float sq = 0.f;
#pragma unroll
      for (int nt = 0; nt < 4; ++nt) {
        const int gn = bn + wn + nt * 16 + m16;
        float v = scv * (acc[mt][nt][r] - c0v * wc0[gn]) + bias[gn];
        Cb[(size_t)gm * N + gn] = f2bf(v);
        sq += (gn == 0) ? 0.f : v * v;
      }
      sq += __shfl_xor(sq, 1, 64);
      sq += __shfl_xor(sq, 2, 64);
      sq += __shfl_xor(sq, 4, 64);
      sq += __shfl_xor(sq, 8, 64);
      if (m16 == 0) part[(size_t)gm * NBLK + 2 * bxi + (wave & 1)] = sq;
    }
  }
}

// ---------------- 256x256 deep-pipelined NT GEMM (T3+T4+T5) ----------------
// 512 threads = 8 waves (2M x 4N); per-wave 128x64 output, acc[8][4].
// LDS: 4-slot ring of (A 256x32 + B 256x32) bf16 = 4 x 32KB = 128KB.
// Tile t computes from slot t&3; tile t+3 staged into slot (t+3)&3 (dead since t-1).
// Per K-tile: 2 phases x {ds_read subtile; 2 global_load_lds; s_barrier;
//   lgkmcnt(0)+sched_barrier(0); setprio(1) 16xMFMA setprio(0); [vmcnt(8)] barrier}.
// vmcnt(8) counted: at end of iter t, outstanding <=8 = loads of iters t-1,t
//   (staging tiles t+2,t+3) -> tile t+1 resident before iter t+1 reads it.
//   Per-wave vmcnt guarantee becomes workgroup-wide via the following s_barrier.
// Never vmcnt(0) in the main loop; single full drain after the loop (LDS freed at endpgm).
// Granule swizzle identical to legacy kernel (measured 0 bank conflicts):
//   LDS granule g of row r holds global granule g ^ ((r>>1)&3).
// Epilogue: y = sc[m]*(acc - c0f[m]*wc0[n]) + bias[n]; partials part[gm*64 + bxi*4 + wc].
template<int N, int K>
__global__ __launch_bounds__(512, 2) void k_gemm256(
    const unsigned short* __restrict__ A,
    const unsigned short* __restrict__ B,
    const float* __restrict__ bias,
    const float* __restrict__ sc,
    const float* __restrict__ c0f,
    const float* __restrict__ wc0,
    unsigned short* __restrict__ Cb,
    float* __restrict__ part)
{
  static_assert(K % 32 == 0 && K / 32 >= 4, "need >=4 K-tiles");
  constexpr int NT = K / 32;
  __shared__ __align__(16) unsigned short S[4][2][8192];   // [slot][A/B][256*32]

  const int tid  = threadIdx.x;
  const int wave = tid >> 6;
  const int lane = tid & 63;
  const int quad = lane >> 4;
  const int m16  = lane & 15;
  const int wr   = wave >> 2;     // 0..1 (M)
  const int wc   = wave & 3;      // 0..3 (N)

  // bijective XCD swizzle: 512 blocks = 8 XCDs x 64; each XCD gets an 8x8 tile patch
  const int j = blockIdx.x & 7;
  const int k = blockIdx.x >> 3;                 // 0..63
  const int bxi = 8 * (j & 1) + (k & 7);         // 0..15  (N/256)
  const int byi = 8 * (j >> 1) + (k >> 3);       // 0..31  (M/256)
  const int bm = byi * 256;
  const int bn = bxi * 256;

  // staging: thread -> row tid>>2 (0..127), LDS granule tid&3; global granule pre-swizzled
  const int gsw8 = (((tid & 3) ^ ((tid >> 3) & 3)) << 3);
  const unsigned short* gA = A + (size_t)(bm + (tid >> 2)) * K + gsw8;
  const unsigned short* gB = B + (size_t)(bn + (tid >> 2)) * K + gsw8;
  const int ld0 = wave * 512;          // rows  wave*16 .. +15
  const int ld1 = 4096 + wave * 512;   // rows 128+wave*16 .. +15

  // read-side swizzle + fragment base offsets (elements)
  const int rsw8 = ((quad ^ ((m16 >> 1) & 3)) << 3);
  const int aoff = (wr * 128 + m16) * 32 + rsw8;
  const int boff = (wc * 64  + m16) * 32 + rsw8;

  floatx4 acc[8][4];
#pragma unroll
  for (int i = 0; i < 8; ++i)
#pragma unroll
    for (int jj = 0; jj < 4; ++jj)
#pragma unroll
      for (int r = 0; r < 4; ++r) acc[i][jj][r] = 0.0f;

#define GLL(SRC, DST) __builtin_amdgcn_global_load_lds((gbl_void_t*)(void*)(SRC), (lds_void_t*)(DST), 16, 0, 0)

  // prologue: stage tiles 0,1,2 (12 loads/thread); wait all but newest 8 -> tile 0 resident
#pragma unroll
  for (int tt = 0; tt < 3; ++tt) {
    const unsigned short* pa = gA + tt * 32;
    const unsigned short* pb = gB + tt * 32;
    GLL(pa,                   &S[tt][0][ld0]);
    GLL(pa + (size_t)128 * K, &S[tt][0][ld1]);
    GLL(pb,                   &S[tt][1][ld0]);
    GLL(pb + (size_t)128 * K, &S[tt][1][ld1]);
  }
  asm volatile("s_waitcnt vmcnt(8)" ::: "memory");
  __builtin_amdgcn_s_barrier();

  for (int t = 0; t < NT; ++t) {
    const int slot = t & 3;
    const int s3   = (t + 3) & 3;
    const unsigned short* Asl = &S[slot][0][0];
    const unsigned short* Bsl = &S[slot][1][0];
    // tail: clamp source tile (re-stages last tile into a dead slot; keeps vmcnt uniform)
    const int kt = ((t + 3 < NT) ? (t + 3) : (NT - 1)) * 32;
    const unsigned short* ga = gA + kt;
    const unsigned short* gb = gB + kt;

    // ---------------- phase A: M-frags 0..3 x all N ----------------
    bf16x8 a[4], b[4];
#pragma unroll
    for (int f = 0; f < 4; ++f) a[f] = *(const bf16x8*)(Asl + aoff + f * 512);
#pragma unroll
    for (int n = 0; n < 4; ++n) b[n] = *(const bf16x8*)(Bsl + boff + n * 512);
    GLL(ga,                   &S[s3][0][ld0]);
    GLL(ga + (size_t)128 * K, &S[s3][0][ld1]);
    __builtin_amdgcn_s_barrier();
    asm volatile("s_waitcnt lgkmcnt(0)" ::: "memory");
    __builtin_amdgcn_sched_barrier(0);
    __builtin_amdgcn_s_setprio(1);
#pragma unroll
    for (int f = 0; f < 4; ++f)
#pragma unroll
      for (int n = 0; n < 4; ++n)
        acc[f][n] = __builtin_amdgcn_mfma_f32_16x16x32_bf16(a[f], b[n], acc[f][n], 0, 0, 0);
    __builtin_amdgcn_s_setprio(0);
    __builtin_amdgcn_s_barrier();

    // ---------------- phase B: M-frags 4..7 x all N (reuse b) ----------------
    bf16x8 a2[4];
#pragma unroll
    for (int f = 0; f < 4; ++f) a2[f] = *(const bf16x8*)(Asl + aoff + 2048 + f * 512);
    GLL(gb,                   &S[s3][1][ld0]);
    GLL(gb + (size_t)128 * K, &S[s3][1][ld1]);
    __builtin_amdgcn_s_barrier();
    asm volatile("s_waitcnt lgkmcnt(0)" ::: "memory");
    __builtin_amdgcn_sched_barrier(0);
    __builtin_amdgcn_s_setprio(1);
#pragma unroll
    for (int f = 0; f < 4; ++f)
#pragma unroll
      for (int n = 0; n < 4; ++n)
        acc[f + 4][n] = __builtin_amdgcn_mfma_f32_16x16x32_bf16(a2[f], b[n], acc[f + 4][n], 0, 0, 0);
    __builtin_amdgcn_s_setprio(0);
    // counted wait: all tiles <= t+1 resident; tiles t+2,t+3 (8 loads) stay in flight
    asm volatile("s_waitcnt vmcnt(8)" ::: "memory");
    __builtin_amdgcn_s_barrier();
  }
#undef GLL

  // drain outstanding global_load_lds before waves can retire (LDS is freed at endpgm)
  asm volatile("s_waitcnt vmcnt(0)" ::: "memory");

  // epilogue: C/D layout col = lane&15, row = quad*4 + r
  const int wm = wr * 128;
  const int wn = wc * 64;
#pragma unroll
  for (int mt = 0; mt < 8; ++mt) {
#pragma unroll
    for (int r = 0; r < 4; ++r) {
      const int gm = bm + wm + mt * 16 + quad * 4 + r;
      const float scv = sc[gm];
      const float c0v = c0f[gm];
      float sq = 0.f;
#pragma unroll
      for (int nt = 0; nt < 4; ++nt) {
        const int gn = bn + wn + nt * 16 + m16;
        float v = scv * (acc[mt][nt][r] - c0v * wc0[gn]) + bias[gn];
        Cb[(size_t)gm * N + gn] = f2bf(v);
        sq += (gn == 0) ? 0.f : v * v;
      }
      sq += __shfl_xor(sq, 1, 64);
      sq += __shfl_xor(sq, 2, 64);
      sq += __shfl_xor(sq, 4, 64);
      sq += __shfl_xor(sq, 8, 64);
      if (m16 == 0) part[(size_t)gm * 64 + bxi * 4 + wc] = sq;
    }
  }
}

extern "C" void kernel_launch(void* const* d_in, const int* in_sizes, int n_in,
                              void* d_out, int out_size, void* d_ws, size_t ws_size,
                              hipStream_t stream) {
  const void* x  = d_in[0];
  const void* W1 = d_in[1];
  const void* b1 = d_in[2];
  const void* W2 = d_in[3];
  const void* b2 = d_in[4];
  const void* W3 = d_in[5];
  const void* b3 = d_in[6];

  const int NR = 8192, DIN = 1024, DH = 4096, DOUT = 1024;

  char* ws = (char*)d_ws;
  size_t off = 0;
  int* mode = (int*)(ws + off);                        off += 256;
  unsigned short* W1b = (unsigned short*)(ws + off);   off += (size_t)DH * DIN * 2;
  unsigned short* W2b = (unsigned short*)(ws + off);   off += (size_t)DH * DH * 2;
  unsigned short* W3b = (unsigned short*)(ws + off);   off += (size_t)DOUT * DH * 2;
  unsigned short* xb  = (unsigned short*)(ws + off);   off += (size_t)NR * DIN * 2;
  unsigned short* y1  = (unsigned short*)(ws + off);   off += (size_t)NR * DH * 2;
  unsigned short* y2  = (unsigned short*)(ws + off);   off += (size_t)NR * DH * 2;
  unsigned short* y3  = (unsigned short*)(ws + off);   off += (size_t)NR * DOUT * 2;
  float* part1 = (float*)(ws + off);                   off += (size_t)NR * 64 * 4;
  float* part2 = (float*)(ws + off);                   off += (size_t)NR * 64 * 4;
  float* part3 = (float*)(ws + off);                   off += (size_t)NR * 16 * 4;
  float* sc0  = (float*)(ws + off);                    off += (size_t)NR * 4;
  float* x0c  = (float*)(ws + off);                    off += (size_t)NR * 4;
  float* sc1  = (float*)(ws + off);                    off += (size_t)NR * 4;
  float* c01  = (float*)(ws + off);                    off += (size_t)NR * 4;
  float* sc2  = (float*)(ws + off);                    off += (size_t)NR * 4;
  float* c02  = (float*)(ws + off);                    off += (size_t)NR * 4;
  float* ss3  = (float*)(ws + off);                    off += (size_t)NR * 4;
  float* w1c0 = (float*)(ws + off);                    off += (size_t)DH * 4;
  float* w2c0 = (float*)(ws + off);                    off += (size_t)DH * 4;
  float* w3c0 = (float*)(ws + off);                    off += (size_t)DOUT * 4;
  float* b1f  = (float*)(ws + off);                    off += (size_t)DH * 4;
  float* b2f  = (float*)(ws + off);                    off += (size_t)DH * 4;
  float* b3f  = (float*)(ws + off);                    off += (size_t)DOUT * 4;

  k_init<<<16, 256, 0, stream>>>((const unsigned short*)x, mode, b1, b2, b3, b1f, b2f, b3f);

  k_cvtw<128><<<(DH * DIN / 8 + 255) / 256, 256, 0, stream>>>(W1, W1b, mode, DH * DIN / 8, w1c0);
  k_cvtw<512><<<(DH * DH  / 8 + 255) / 256, 256, 0, stream>>>(W2, W2b, mode, DH * DH / 8, w2c0);
  k_cvtw<512><<<(DOUT * DH / 8 + 255) / 256, 256, 0, stream>>>(W3, W3b, mode, DOUT * DH / 8, w3c0);

  k_prep<<<NR, 256, 0, stream>>>(x, xb, sc0, x0c, mode);

  k_gemm256<4096, 1024><<<512, 512, 0, stream>>>(
      xb, W1b, b1f, sc0, x0c, w1c0, y1, part1);
  k_sc<64><<<(NR + 255) / 256, 256, 0, stream>>>(part1, y1, DH, sc1, c01, nullptr, NR);

  k_gemm256<4096, 4096><<<512, 512, 0, stream>>>(
      y1, W2b, b2f, sc1, c01, w2c0, y2, part2);
  k_sc<64><<<(NR + 255) / 256, 256, 0, stream>>>(part2, y2, DH, sc2, c02, nullptr, NR);

  k_gemm_bt<1024, 4096, 16, 8><<<512, 256, 0, stream>>>(
      y2, W3b, b3f, sc2, c02, w3c0, y3, part3);
  k_sc<16><<<(NR + 255) / 256, 256, 0, stream>>>(part3, y3, DOUT, sc0, x0c, ss3, NR);

  k_final<<<NR, 256, 0, stream>>>(y3, ss3, d_out, mode);
}

// Round 3
// 603.931 us; speedup vs baseline: 1.1078x; 1.0047x over previous
//
#include <hip/hip_runtime.h>
#include <stdint.h>

#define EPSF 1e-7f
#define MAXTAN 10.0f

typedef __bf16 bf16x8 __attribute__((ext_vector_type(8)));
typedef float floatx4 __attribute__((ext_vector_type(4)));
typedef __attribute__((address_space(3))) void lds_void_t;
typedef __attribute__((address_space(1))) void gbl_void_t;

__device__ __forceinline__ unsigned short f2bf(float x) {
  union { float f; uint32_t u; } v; v.f = x;
  uint32_t u = v.u;
  u += 0x7fffu + ((u >> 16) & 1u);   // RNE
  return (unsigned short)(u >> 16);
}
__device__ __forceinline__ float bf2f(unsigned short h) {
  union { uint32_t u; float f; } v; v.u = ((uint32_t)h) << 16;
  return v.f;
}

__device__ __forceinline__ int sniff_mode(const unsigned short* x) {
  int sane = 0;
  for (int i = 0; i < 128; ++i) {
    unsigned short h = x[i];
    int e = (h >> 7) & 0xFF;
    if ((h & 0x7FFF) == 0 || (e >= 96 && e <= 140)) ++sane;
  }
  return (sane >= 120) ? 1 : 0;
}

// ---------------- init: sniff dtype + convert biases ----------------
__global__ void k_init(const unsigned short* __restrict__ x, int* __restrict__ modeg,
                       const void* __restrict__ b1, const void* __restrict__ b2,
                       const void* __restrict__ b3, float* __restrict__ o1,
                       float* __restrict__ o2, float* __restrict__ o3) {
  __shared__ int mds;
  if (threadIdx.x == 0) {
    int m = sniff_mode(x);
    mds = m;
    if (blockIdx.x == 0) *modeg = m;
  }
  __syncthreads();
  int m = mds;
  int i = blockIdx.x * 256 + threadIdx.x;
  if (i < 4096) o1[i] = m ? bf2f(((const unsigned short*)b1)[i]) : ((const float*)b1)[i];
  if (i < 4096) o2[i] = m ? bf2f(((const unsigned short*)b2)[i]) : ((const float*)b2)[i];
  if (i < 1024) o3[i] = m ? bf2f(((const unsigned short*)b3)[i]) : ((const float*)b3)[i];
}

// ---------------- x prep: convert to bf16, compute logmap scale + x0 ----------------
__global__ void k_prep(const void* __restrict__ xv, unsigned short* __restrict__ xb,
                       float* __restrict__ sc0, float* __restrict__ x0c,
                       const int* __restrict__ mode) {
  const int row = blockIdx.x;
  const int tid = threadIdx.x;
  float4 v;
  if (*mode) {
    ushort4 u = ((const ushort4*)((const unsigned short*)xv + (size_t)row * 1024))[tid];
    v.x = bf2f(u.x); v.y = bf2f(u.y); v.z = bf2f(u.z); v.w = bf2f(u.w);
  } else {
    v = ((const float4*)((const float*)xv + (size_t)row * 1024))[tid];
  }
  ushort4 o;
  o.x = f2bf(v.x); o.y = f2bf(v.y); o.z = f2bf(v.z); o.w = f2bf(v.w);
  ((ushort4*)(xb + (size_t)row * 1024))[tid] = o;

  float s = v.x * v.x + v.y * v.y + v.z * v.z + v.w * v.w;
  if (tid == 0) s -= v.x * v.x;          // exclude time coordinate
  for (int off = 32; off; off >>= 1) s += __shfl_down(s, off, 64);
  __shared__ float red[4];
  if ((tid & 63) == 0) red[tid >> 6] = s;
  __syncthreads();
  if (tid == 0) {
    s = red[0] + red[1] + red[2] + red[3];
    float ns = fmaxf(sqrtf(s), EPSF);
    float d = acoshf(fmaxf(v.x, 1.0f + EPSF));
    sc0[row] = d / ns;
    x0c[row] = bf2f(o.x);
  }
}

// ---------------- weight convert to bf16 + col0 extraction ----------------
template<int K8>
__global__ void k_cvtw(const void* __restrict__ in, unsigned short* __restrict__ out,
                       const int* __restrict__ mode, int n8, float* __restrict__ c0) {
  int i = blockIdx.x * 256 + threadIdx.x;
  if (i >= n8) return;
  if (*mode) {
    uint4 g = ((const uint4*)in)[i];
    ((uint4*)out)[i] = g;
    if (i % K8 == 0) c0[i / K8] = bf2f((unsigned short)(g.x & 0xFFFFu));
  } else {
    float4 a = ((const float4*)in)[2 * i];
    float4 b = ((const float4*)in)[2 * i + 1];
    ushort4 oa, ob;
    oa.x = f2bf(a.x); oa.y = f2bf(a.y); oa.z = f2bf(a.z); oa.w = f2bf(a.w);
    ob.x = f2bf(b.x); ob.y = f2bf(b.y); ob.z = f2bf(b.z); ob.w = f2bf(b.w);
    ((ushort4*)out)[2 * i] = oa;
    ((ushort4*)out)[2 * i + 1] = ob;
    if (i % K8 == 0) c0[i / K8] = bf2f(oa.x);
  }
}

// ---------------- partial-sumsq fold -> scale + col0 grab ----------------
template<int NBLK>
__global__ void k_sc(const float* __restrict__ part, const unsigned short* __restrict__ y,
                     int stride, float* __restrict__ sc, float* __restrict__ c0,
                     float* __restrict__ ssout, int nrows) {
  int i = blockIdx.x * 256 + threadIdx.x;
  if (i >= nrows) return;
  float s = 0.f;
#pragma unroll
  for (int j = 0; j < NBLK; ++j) s += part[(size_t)i * NBLK + j];
  float n = fmaxf(sqrtf(fmaxf(s, 0.f)), EPSF);
  sc[i] = fminf(n, MAXTAN) / n;
  c0[i] = bf2f(y[(size_t)i * stride]);
  if (ssout) ssout[i] = s;
}

// ---------------- final: y3 bf16 + ss3 -> projx(safe_expmap0(y3)) ----------------
__global__ void k_final(const unsigned short* __restrict__ y, const float* __restrict__ ss,
                        void* __restrict__ outv, const int* __restrict__ mode) {
  const int row = blockIdx.x;
  const int tid = threadIdx.x;
  float n = fmaxf(sqrtf(fmaxf(ss[row], 0.f)), EPSF);
  float nc = fminf(n, MAXTAN);
  float a = sinhf(nc) / n;
  ushort4 u = ((const ushort4*)(y + (size_t)row * 1024))[tid];
  float4 o;
  o.x = bf2f(u.x) * a; o.y = bf2f(u.y) * a;
  o.z = bf2f(u.z) * a; o.w = bf2f(u.w) * a;
  if (tid == 0) o.x = coshf(nc);
  if (*mode) {
    ushort4 o16;
    o16.x = f2bf(o.x); o16.y = f2bf(o.y); o16.z = f2bf(o.z); o16.w = f2bf(o.w);
    ((ushort4*)outv)[(size_t)row * 256 + tid] = o16;
  } else {
    ((float4*)outv)[(size_t)row * 256 + tid] = o;
  }
}

// ---------------- legacy 128x128 NT GEMM (kept for GEMM3: N=1024 grid too small for 256^2) ----------------
template<int N, int K, int NBLK, int GX>
__global__ __launch_bounds__(256, 4) void k_gemm_bt(
    const unsigned short* __restrict__ A,
    const unsigned short* __restrict__ B,
    const float* __restrict__ bias,
    const float* __restrict__ sc,
    const float* __restrict__ c0f,
    const float* __restrict__ wc0,
    unsigned short* __restrict__ Cb,
    float* __restrict__ part)
{
  __shared__ __align__(16) unsigned short As[128 * 32];
  __shared__ __align__(16) unsigned short Bs[128 * 32];

  const int tid  = threadIdx.x;
  const int wave = tid >> 6;
  const int lane = tid & 63;
  const int quad = lane >> 4;
  const int m16  = lane & 15;

  const int j = blockIdx.x & 7;
  const int k = blockIdx.x >> 3;
  int bxi, byi;
  if (GX == 32) {
    bxi = 16 * (j & 1) + (k & 15);
    byi = 16 * (j >> 1) + (k >> 4);
  } else {
    bxi = k & 7;
    byi = 8 * j + (k >> 3);
  }
  const int bm = byi * 128;
  const int bn = bxi * 128;

  const int srow = lane >> 2;
  const int scol = (((lane & 3) ^ ((srow >> 1) & 3)) << 3);

  const int wm = (wave >> 1) << 6;
  const int wn = (wave & 1) << 6;

  const int rsw = ((quad ^ ((m16 >> 1) & 3)) << 3);

  const int c0i = wave * 2;
  const unsigned short* ga0 = A + (size_t)(bm + c0i * 16 + srow) * K + scol;
  const unsigned short* ga1 = ga0 + (size_t)16 * K;
  const unsigned short* gb0 = B + (size_t)(bn + c0i * 16 + srow) * K + scol;
  const unsigned short* gb1 = gb0 + (size_t)16 * K;

  floatx4 acc[4][4];
#pragma unroll
  for (int i = 0; i < 4; ++i)
#pragma unroll
    for (int jj = 0; jj < 4; ++jj)
#pragma unroll
      for (int r = 0; r < 4; ++r) acc[i][jj][r] = 0.0f;

  for (int k0 = 0; k0 < K; k0 += 32) {
    __builtin_amdgcn_global_load_lds((gbl_void_t*)(void*)ga0,
                                     (lds_void_t*)(As + c0i * 512), 16, 0, 0);
    __builtin_amdgcn_global_load_lds((gbl_void_t*)(void*)ga1,
                                     (lds_void_t*)(As + c0i * 512 + 512), 16, 0, 0);
    __builtin_amdgcn_global_load_lds((gbl_void_t*)(void*)gb0,
                                     (lds_void_t*)(Bs + c0i * 512), 16, 0, 0);
    __builtin_amdgcn_global_load_lds((gbl_void_t*)(void*)gb1,
                                     (lds_void_t*)(Bs + c0i * 512 + 512), 16, 0, 0);
    ga0 += 32; ga1 += 32; gb0 += 32; gb1 += 32;
    __syncthreads();

    bf16x8 af[4], bfg[4];
#pragma unroll
    for (int t = 0; t < 4; ++t) {
      af[t]  = *(const bf16x8*)(As + (wm + t * 16 + m16) * 32 + rsw);
      bfg[t] = *(const bf16x8*)(Bs + (wn + t * 16 + m16) * 32 + rsw);
    }
#pragma unroll
    for (int mt = 0; mt < 4; ++mt)
#pragma unroll
      for (int nt = 0; nt < 4; ++nt)
        acc[mt][nt] = __builtin_amdgcn_mfma_f32_16x16x32_bf16(af[mt], bfg[nt], acc[mt][nt], 0, 0, 0);
    __syncthreads();
  }

#pragma unroll
  for (int mt = 0; mt < 4; ++mt) {
#pragma unroll
    for (int r = 0; r < 4; ++r) {
      const int gm = bm + wm + mt * 16 + quad * 4 + r;
      const float scv = sc[gm];
      const float c0v = c0f[gm];
      float sq = 0.f;
#pragma unroll
      for (int nt = 0; nt < 4; ++nt) {
        const int gn = bn + wn + nt * 16 + m16;
        float v = scv * (acc[mt][nt][r] - c0v * wc0[gn]) + bias[gn];
        Cb[(size_t)gm * N + gn] = f2bf(v);
        sq += (gn == 0) ? 0.f : v * v;
      }
      sq += __shfl_xor(sq, 1, 64);
      sq += __shfl_xor(sq, 2, 64);
      sq += __shfl_xor(sq, 4, 64);
      sq += __shfl_xor(sq, 8, 64);
      if (m16 == 0) part[(size_t)gm * NBLK + 2 * bxi + (wave & 1)] = sq;
    }
  }
}

// ---------------- 256x256 deep-pipelined NT GEMM (T3+T4+T5) ----------------
// 512 threads = 8 waves (2M x 4N); per-wave 128x64 output, acc[8][4].
// LDS: 4-slot ring of (A 256x32 + B 256x32) bf16 = 4 x 32KB = 128KB.
// Tile t computes from slot t&3; tile t+3 staged into slot (t+3)&3 (dead since t-1).
// Per K-tile: 2 phases x {2 global_load_lds; ds_read subtile; s_barrier;
//   setprio(1) 16xMFMA setprio(0); [vmcnt(8)] s_barrier}.
// R3 change (m141 evidence): NO sched_barrier(0) / asm lgkmcnt(0) pins -- the
//   compiler's fine-grained lgkmcnt(N) lets MFMAs start while later ds_reads are
//   still in flight, overlapping the read window with the matrix pipe.
// Safety: the per-iter `asm vmcnt(8) ::: "memory"` is a full memory-op fence at
//   every iteration boundary (no ds_read/GLL crosses iters); within an iter all
//   reads hit slot t&3, all GLL writes hit slot (t+3)&3 -- disjoint.
// vmcnt(8) counted: at end of iter t, outstanding <=8 = loads of iters t-1,t
//   (staging tiles t+2,t+3) -> tile t+1 resident before iter t+1 reads it.
//   Per-wave vmcnt guarantee becomes workgroup-wide via the following s_barrier.
// Granule swizzle (measured 0 conflicts): LDS granule g of row r = global g ^ ((r>>1)&3).
// Epilogue: y = sc[m]*(acc - c0f[m]*wc0[n]) + bias[n]; partials part[gm*64 + bxi*4 + wc].
template<int N, int K>
__global__ __launch_bounds__(512, 2) void k_gemm256(
    const unsigned short* __restrict__ A,
    const unsigned short* __restrict__ B,
    const float* __restrict__ bias,
    const float* __restrict__ sc,
    const float* __restrict__ c0f,
    const float* __restrict__ wc0,
    unsigned short* __restrict__ Cb,
    float* __restrict__ part)
{
  static_assert(K % 32 == 0 && K / 32 >= 4, "need >=4 K-tiles");
  constexpr int NT = K / 32;
  __shared__ __align__(16) unsigned short S[4][2][8192];   // [slot][A/B][256*32]

  const int tid  = threadIdx.x;
  const int wave = tid >> 6;
  const int lane = tid & 63;
  const int quad = lane >> 4;
  const int m16  = lane & 15;
  const int wr   = wave >> 2;     // 0..1 (M)
  const int wc   = wave & 3;      // 0..3 (N)

  // bijective XCD swizzle: 512 blocks = 8 XCDs x 64; each XCD gets an 8x8 tile patch
  const int j = blockIdx.x & 7;
  const int k = blockIdx.x >> 3;                 // 0..63
  const int bxi = 8 * (j & 1) + (k & 7);         // 0..15  (N/256)
  const int byi = 8 * (j >> 1) + (k >> 3);       // 0..31  (M/256)
  const int bm = byi * 256;
  const int bn = bxi * 256;

  // staging: thread -> row tid>>2 (0..127), LDS granule tid&3; global granule pre-swizzled
  const int gsw8 = (((tid & 3) ^ ((tid >> 3) & 3)) << 3);
  const unsigned short* gA = A + (size_t)(bm + (tid >> 2)) * K + gsw8;
  const unsigned short* gB = B + (size_t)(bn + (tid >> 2)) * K + gsw8;
  const int ld0 = wave * 512;          // rows  wave*16 .. +15
  const int ld1 = 4096 + wave * 512;   // rows 128+wave*16 .. +15

  // read-side swizzle + fragment base offsets (elements)
  const int rsw8 = ((quad ^ ((m16 >> 1) & 3)) << 3);
  const int aoff = (wr * 128 + m16) * 32 + rsw8;
  const int boff = (wc * 64  + m16) * 32 + rsw8;

  floatx4 acc[8][4];
#pragma unroll
  for (int i = 0; i < 8; ++i)
#pragma unroll
    for (int jj = 0; jj < 4; ++jj)
#pragma unroll
      for (int r = 0; r < 4; ++r) acc[i][jj][r] = 0.0f;

#define GLL(SRC, DST) __builtin_amdgcn_global_load_lds((gbl_void_t*)(void*)(SRC), (lds_void_t*)(DST), 16, 0, 0)

  // prologue: stage tiles 0,1,2 (12 loads/thread); wait all but newest 8 -> tile 0 resident
#pragma unroll
  for (int tt = 0; tt < 3; ++tt) {
    const unsigned short* pa = gA + tt * 32;
    const unsigned short* pb = gB + tt * 32;
    GLL(pa,                   &S[tt][0][ld0]);
    GLL(pa + (size_t)128 * K, &S[tt][0][ld1]);
    GLL(pb,                   &S[tt][1][ld0]);
    GLL(pb + (size_t)128 * K, &S[tt][1][ld1]);
  }
  asm volatile("s_waitcnt vmcnt(8)" ::: "memory");
  __builtin_amdgcn_s_barrier();

  for (int t = 0; t < NT; ++t) {
    const int slot = t & 3;
    const int s3   = (t + 3) & 3;
    const unsigned short* Asl = &S[slot][0][0];
    const unsigned short* Bsl = &S[slot][1][0];
    // tail: clamp source tile (re-stages last tile into a dead slot; keeps vmcnt uniform)
    const int kt = ((t + 3 < NT) ? (t + 3) : (NT - 1)) * 32;
    const unsigned short* ga = gA + kt;
    const unsigned short* gb = gB + kt;

    // ---------------- phase A: M-frags 0..3 x all N ----------------
    GLL(ga,                   &S[s3][0][ld0]);
    GLL(ga + (size_t)128 * K, &S[s3][0][ld1]);
    bf16x8 a[4], b[4];
#pragma unroll
    for (int f = 0; f < 4; ++f) a[f] = *(const bf16x8*)(Asl + aoff + f * 512);
#pragma unroll
    for (int n = 0; n < 4; ++n) b[n] = *(const bf16x8*)(Bsl + boff + n * 512);
    __builtin_amdgcn_s_barrier();
    __builtin_amdgcn_s_setprio(1);
#pragma unroll
    for (int f = 0; f < 4; ++f)
#pragma unroll
      for (int n = 0; n < 4; ++n)
        acc[f][n] = __builtin_amdgcn_mfma_f32_16x16x32_bf16(a[f], b[n], acc[f][n], 0, 0, 0);
    __builtin_amdgcn_s_setprio(0);
    __builtin_amdgcn_s_barrier();

    // ---------------- phase B: M-frags 4..7 x all N (reuse b) ----------------
    GLL(gb,                   &S[s3][1][ld0]);
    GLL(gb + (size_t)128 * K, &S[s3][1][ld1]);
    bf16x8 a2[4];
#pragma unroll
    for (int f = 0; f < 4; ++f) a2[f] = *(const bf16x8*)(Asl + aoff + 2048 + f * 512);
    __builtin_amdgcn_s_barrier();
    __builtin_amdgcn_s_setprio(1);
#pragma unroll
    for (int f = 0; f < 4; ++f)
#pragma unroll
      for (int n = 0; n < 4; ++n)
        acc[f + 4][n] = __builtin_amdgcn_mfma_f32_16x16x32_bf16(a2[f], b[n], acc[f + 4][n], 0, 0, 0);
    __builtin_amdgcn_s_setprio(0);
    // counted wait: all tiles <= t+1 resident; tiles t+2,t+3 (8 loads) stay in flight.
    // This inline asm (memory clobber) is also the per-iteration reorder fence.
    asm volatile("s_waitcnt vmcnt(8)" ::: "memory");
    __builtin_amdgcn_s_barrier();
  }
#undef GLL

  // drain outstanding global_load_lds before waves can retire (LDS is freed at endpgm)
  asm volatile("s_waitcnt vmcnt(0)" ::: "memory");

  // epilogue: C/D layout col = lane&15, row = quad*4 + r
  const int wm = wr * 128;
  const int wn = wc * 64;
#pragma unroll
  for (int mt = 0; mt < 8; ++mt) {
#pragma unroll
    for (int r = 0; r < 4; ++r) {
      const int gm = bm + wm + mt * 16 + quad * 4 + r;
      const float scv = sc[gm];
      const float c0v = c0f[gm];
      float sq = 0.f;
#pragma unroll
      for (int nt = 0; nt < 4; ++nt) {
        const int gn = bn + wn + nt * 16 + m16;
        float v = scv * (acc[mt][nt][r] - c0v * wc0[gn]) + bias[gn];
        Cb[(size_t)gm * N + gn] = f2bf(v);
        sq += (gn == 0) ? 0.f : v * v;
      }
      sq += __shfl_xor(sq, 1, 64);
      sq += __shfl_xor(sq, 2, 64);
      sq += __shfl_xor(sq, 4, 64);
      sq += __shfl_xor(sq, 8, 64);
      if (m16 == 0) part[(size_t)gm * 64 + bxi * 4 + wc] = sq;
    }
  }
}

extern "C" void kernel_launch(void* const* d_in, const int* in_sizes, int n_in,
                              void* d_out, int out_size, void* d_ws, size_t ws_size,
                              hipStream_t stream) {
  const void* x  = d_in[0];
  const void* W1 = d_in[1];
  const void* b1 = d_in[2];
  const void* W2 = d_in[3];
  const void* b2 = d_in[4];
  const void* W3 = d_in[5];
  const void* b3 = d_in[6];

  const int NR = 8192, DIN = 1024, DH = 4096, DOUT = 1024;

  char* ws = (char*)d_ws;
  size_t off = 0;
  int* mode = (int*)(ws + off);                        off += 256;
  unsigned short* W1b = (unsigned short*)(ws + off);   off += (size_t)DH * DIN * 2;
  unsigned short* W2b = (unsigned short*)(ws + off);   off += (size_t)DH * DH * 2;
  unsigned short* W3b = (unsigned short*)(ws + off);   off += (size_t)DOUT * DH * 2;
  unsigned short* xb  = (unsigned short*)(ws + off);   off += (size_t)NR * DIN * 2;
  unsigned short* y1  = (unsigned short*)(ws + off);   off += (size_t)NR * DH * 2;
  unsigned short* y2  = (unsigned short*)(ws + off);   off += (size_t)NR * DH * 2;
  unsigned short* y3  = (unsigned short*)(ws + off);   off += (size_t)NR * DOUT * 2;
  float* part1 = (float*)(ws + off);                   off += (size_t)NR * 64 * 4;
  float* part2 = (float*)(ws + off);                   off += (size_t)NR * 64 * 4;
  float* part3 = (float*)(ws + off);                   off += (size_t)NR * 16 * 4;
  float* sc0  = (float*)(ws + off);                    off += (size_t)NR * 4;
  float* x0c  = (float*)(ws + off);                    off += (size_t)NR * 4;
  float* sc1  = (float*)(ws + off);                    off += (size_t)NR * 4;
  float* c01  = (float*)(ws + off);                    off += (size_t)NR * 4;
  float* sc2  = (float*)(ws + off);                    off += (size_t)NR * 4;
  float* c02  = (float*)(ws + off);                    off += (size_t)NR * 4;
  float* ss3  = (float*)(ws + off);                    off += (size_t)NR * 4;
  float* w1c0 = (float*)(ws + off);                    off += (size_t)DH * 4;
  float* w2c0 = (float*)(ws + off);                    off += (size_t)DH * 4;
  float* w3c0 = (float*)(ws + off);                    off += (size_t)DOUT * 4;
  float* b1f  = (float*)(ws + off);                    off += (size_t)DH * 4;
  float* b2f  = (float*)(ws + off);                    off += (size_t)DH * 4;
  float* b3f  = (float*)(ws + off);                    off += (size_t)DOUT * 4;

  k_init<<<16, 256, 0, stream>>>((const unsigned short*)x, mode, b1, b2, b3, b1f, b2f, b3f);

  k_cvtw<128><<<(DH * DIN / 8 + 255) / 256, 256, 0, stream>>>(W1, W1b, mode, DH * DIN / 8, w1c0);
  k_cvtw<512><<<(DH * DH  / 8 + 255) / 256, 256, 0, stream>>>(W2, W2b, mode, DH * DH / 8, w2c0);
  k_cvtw<512><<<(DOUT * DH / 8 + 255) / 256, 256, 0, stream>>>(W3, W3b, mode, DOUT * DH / 8, w3c0);

  k_prep<<<NR, 256, 0, stream>>>(x, xb, sc0, x0c, mode);

  k_gemm256<4096, 1024><<<512, 512, 0, stream>>>(
      xb, W1b, b1f, sc0, x0c, w1c0, y1, part1);
  k_sc<64><<<(NR + 255) / 256, 256, 0, stream>>>(part1, y1, DH, sc1, c01, nullptr, NR);

  k_gemm256<4096, 4096><<<512, 512, 0, stream>>>(
      y1, W2b, b2f, sc1, c01, w2c0, y2, part2);
  k_sc<64><<<(NR + 255) / 256, 256, 0, stream>>>(part2, y2, DH, sc2, c02, nullptr, NR);

  k_gemm_bt<1024, 4096, 16, 8><<<512, 256, 0, stream>>>(
      y2, W3b, b3f, sc2, c02, w3c0, y3, part3);
  k_sc<16><<<(NR + 255) / 256, 256, 0, stream>>>(part3, y3, DOUT, sc0, x0c, ss3, NR);

  k_final<<<NR, 256, 0, stream>>>(y3, ss3, d_out, mode);
}

// Round 4
// 601.902 us; speedup vs baseline: 1.1115x; 1.0034x over previous
//
#include <hip/hip_runtime.h>
#include <stdint.h>

#define EPSF 1e-7f
#define MAXTAN 10.0f

typedef __bf16 bf16x8 __attribute__((ext_vector_type(8)));
typedef float floatx4 __attribute__((ext_vector_type(4)));
typedef __attribute__((address_space(3))) void lds_void_t;
typedef __attribute__((address_space(1))) void gbl_void_t;

__device__ __forceinline__ unsigned short f2bf(float x) {
  union { float f; uint32_t u; } v; v.f = x;
  uint32_t u = v.u;
  u += 0x7fffu + ((u >> 16) & 1u);   // RNE
  return (unsigned short)(u >> 16);
}
__device__ __forceinline__ float bf2f(unsigned short h) {
  union { uint32_t u; float f; } v; v.u = ((uint32_t)h) << 16;
  return v.f;
}

__device__ __forceinline__ int sniff_mode(const unsigned short* x) {
  int sane = 0;
  for (int i = 0; i < 128; ++i) {
    unsigned short h = x[i];
    int e = (h >> 7) & 0xFF;
    if ((h & 0x7FFF) == 0 || (e >= 96 && e <= 140)) ++sane;
  }
  return (sane >= 120) ? 1 : 0;
}

// ---------------- init: sniff dtype + convert biases ----------------
__global__ void k_init(const unsigned short* __restrict__ x, int* __restrict__ modeg,
                       const void* __restrict__ b1, const void* __restrict__ b2,
                       const void* __restrict__ b3, float* __restrict__ o1,
                       float* __restrict__ o2, float* __restrict__ o3) {
  __shared__ int mds;
  if (threadIdx.x == 0) {
    int m = sniff_mode(x);
    mds = m;
    if (blockIdx.x == 0) *modeg = m;
  }
  __syncthreads();
  int m = mds;
  int i = blockIdx.x * 256 + threadIdx.x;
  if (i < 4096) o1[i] = m ? bf2f(((const unsigned short*)b1)[i]) : ((const float*)b1)[i];
  if (i < 4096) o2[i] = m ? bf2f(((const unsigned short*)b2)[i]) : ((const float*)b2)[i];
  if (i < 1024) o3[i] = m ? bf2f(((const unsigned short*)b3)[i]) : ((const float*)b3)[i];
}

// ---------------- x prep: convert to bf16, compute logmap scale + x0 ----------------
__global__ void k_prep(const void* __restrict__ xv, unsigned short* __restrict__ xb,
                       float* __restrict__ sc0, float* __restrict__ x0c,
                       const int* __restrict__ mode) {
  const int row = blockIdx.x;
  const int tid = threadIdx.x;
  float4 v;
  if (*mode) {
    ushort4 u = ((const ushort4*)((const unsigned short*)xv + (size_t)row * 1024))[tid];
    v.x = bf2f(u.x); v.y = bf2f(u.y); v.z = bf2f(u.z); v.w = bf2f(u.w);
  } else {
    v = ((const float4*)((const float*)xv + (size_t)row * 1024))[tid];
  }
  ushort4 o;
  o.x = f2bf(v.x); o.y = f2bf(v.y); o.z = f2bf(v.z); o.w = f2bf(v.w);
  ((ushort4*)(xb + (size_t)row * 1024))[tid] = o;

  float s = v.x * v.x + v.y * v.y + v.z * v.z + v.w * v.w;
  if (tid == 0) s -= v.x * v.x;          // exclude time coordinate
  for (int off = 32; off; off >>= 1) s += __shfl_down(s, off, 64);
  __shared__ float red[4];
  if ((tid & 63) == 0) red[tid >> 6] = s;
  __syncthreads();
  if (tid == 0) {
    s = red[0] + red[1] + red[2] + red[3];
    float ns = fmaxf(sqrtf(s), EPSF);
    float d = acoshf(fmaxf(v.x, 1.0f + EPSF));
    sc0[row] = d / ns;
    x0c[row] = bf2f(o.x);
  }
}

// ---------------- weight convert to bf16 + col0 extraction ----------------
template<int K8>
__global__ void k_cvtw(const void* __restrict__ in, unsigned short* __restrict__ out,
                       const int* __restrict__ mode, int n8, float* __restrict__ c0) {
  int i = blockIdx.x * 256 + threadIdx.x;
  if (i >= n8) return;
  if (*mode) {
    uint4 g = ((const uint4*)in)[i];
    ((uint4*)out)[i] = g;
    if (i % K8 == 0) c0[i / K8] = bf2f((unsigned short)(g.x & 0xFFFFu));
  } else {
    float4 a = ((const float4*)in)[2 * i];
    float4 b = ((const float4*)in)[2 * i + 1];
    ushort4 oa, ob;
    oa.x = f2bf(a.x); oa.y = f2bf(a.y); oa.z = f2bf(a.z); oa.w = f2bf(a.w);
    ob.x = f2bf(b.x); ob.y = f2bf(b.y); ob.z = f2bf(b.z); ob.w = f2bf(b.w);
    ((ushort4*)out)[2 * i] = oa;
    ((ushort4*)out)[2 * i + 1] = ob;
    if (i % K8 == 0) c0[i / K8] = bf2f(oa.x);
  }
}

// ---------------- partial-sumsq fold -> scale + col0 grab ----------------
template<int NBLK>
__global__ void k_sc(const float* __restrict__ part, const unsigned short* __restrict__ y,
                     int stride, float* __restrict__ sc, float* __restrict__ c0,
                     float* __restrict__ ssout, int nrows) {
  int i = blockIdx.x * 256 + threadIdx.x;
  if (i >= nrows) return;
  float s = 0.f;
#pragma unroll
  for (int j = 0; j < NBLK; ++j) s += part[(size_t)i * NBLK + j];
  float n = fmaxf(sqrtf(fmaxf(s, 0.f)), EPSF);
  sc[i] = fminf(n, MAXTAN) / n;
  c0[i] = bf2f(y[(size_t)i * stride]);
  if (ssout) ssout[i] = s;
}

// ---------------- final: y3 bf16 + ss3 -> projx(safe_expmap0(y3)) ----------------
__global__ void k_final(const unsigned short* __restrict__ y, const float* __restrict__ ss,
                        void* __restrict__ outv, const int* __restrict__ mode) {
  const int row = blockIdx.x;
  const int tid = threadIdx.x;
  float n = fmaxf(sqrtf(fmaxf(ss[row], 0.f)), EPSF);
  float nc = fminf(n, MAXTAN);
  float a = sinhf(nc) / n;
  ushort4 u = ((const ushort4*)(y + (size_t)row * 1024))[tid];
  float4 o;
  o.x = bf2f(u.x) * a; o.y = bf2f(u.y) * a;
  o.z = bf2f(u.z) * a; o.w = bf2f(u.w) * a;
  if (tid == 0) o.x = coshf(nc);
  if (*mode) {
    ushort4 o16;
    o16.x = f2bf(o.x); o16.y = f2bf(o.y); o16.z = f2bf(o.z); o16.w = f2bf(o.w);
    ((ushort4*)outv)[(size_t)row * 256 + tid] = o16;
  } else {
    ((float4*)outv)[(size_t)row * 256 + tid] = o;
  }
}

// ---------------- legacy 128x128 NT GEMM (kept for GEMM3: N=1024 grid too small for 256^2) ----------------
template<int N, int K, int NBLK, int GX>
__global__ __launch_bounds__(256, 4) void k_gemm_bt(
    const unsigned short* __restrict__ A,
    const unsigned short* __restrict__ B,
    const float* __restrict__ bias,
    const float* __restrict__ sc,
    const float* __restrict__ c0f,
    const float* __restrict__ wc0,
    unsigned short* __restrict__ Cb,
    float* __restrict__ part)
{
  __shared__ __align__(16) unsigned short As[128 * 32];
  __shared__ __align__(16) unsigned short Bs[128 * 32];

  const int tid  = threadIdx.x;
  const int wave = tid >> 6;
  const int lane = tid & 63;
  const int quad = lane >> 4;
  const int m16  = lane & 15;

  const int j = blockIdx.x & 7;
  const int k = blockIdx.x >> 3;
  int bxi, byi;
  if (GX == 32) {
    bxi = 16 * (j & 1) + (k & 15);
    byi = 16 * (j >> 1) + (k >> 4);
  } else {
    bxi = k & 7;
    byi = 8 * j + (k >> 3);
  }
  const int bm = byi * 128;
  const int bn = bxi * 128;

  const int srow = lane >> 2;
  const int scol = (((lane & 3) ^ ((srow >> 1) & 3)) << 3);

  const int wm = (wave >> 1) << 6;
  const int wn = (wave & 1) << 6;

  const int rsw = ((quad ^ ((m16 >> 1) & 3)) << 3);

  const int c0i = wave * 2;
  const unsigned short* ga0 = A + (size_t)(bm + c0i * 16 + srow) * K + scol;
  const unsigned short* ga1 = ga0 + (size_t)16 * K;
  const unsigned short* gb0 = B + (size_t)(bn + c0i * 16 + srow) * K + scol;
  const unsigned short* gb1 = gb0 + (size_t)16 * K;

  floatx4 acc[4][4];
#pragma unroll
  for (int i = 0; i < 4; ++i)
#pragma unroll
    for (int jj = 0; jj < 4; ++jj)
#pragma unroll
      for (int r = 0; r < 4; ++r) acc[i][jj][r] = 0.0f;

  for (int k0 = 0; k0 < K; k0 += 32) {
    __builtin_amdgcn_global_load_lds((gbl_void_t*)(void*)ga0,
                                     (lds_void_t*)(As + c0i * 512), 16, 0, 0);
    __builtin_amdgcn_global_load_lds((gbl_void_t*)(void*)ga1,
                                     (lds_void_t*)(As + c0i * 512 + 512), 16, 0, 0);
    __builtin_amdgcn_global_load_lds((gbl_void_t*)(void*)gb0,
                                     (lds_void_t*)(Bs + c0i * 512), 16, 0, 0);
    __builtin_amdgcn_global_load_lds((gbl_void_t*)(void*)gb1,
                                     (lds_void_t*)(Bs + c0i * 512 + 512), 16, 0, 0);
    ga0 += 32; ga1 += 32; gb0 += 32; gb1 += 32;
    __syncthreads();

    bf16x8 af[4], bfg[4];
#pragma unroll
    for (int t = 0; t < 4; ++t) {
      af[t]  = *(const bf16x8*)(As + (wm + t * 16 + m16) * 32 + rsw);
      bfg[t] = *(const bf16x8*)(Bs + (wn + t * 16 + m16) * 32 + rsw);
    }
#pragma unroll
    for (int mt = 0; mt < 4; ++mt)
#pragma unroll
      for (int nt = 0; nt < 4; ++nt)
        acc[mt][nt] = __builtin_amdgcn_mfma_f32_16x16x32_bf16(af[mt], bfg[nt], acc[mt][nt], 0, 0, 0);
    __syncthreads();
  }

#pragma unroll
  for (int mt = 0; mt < 4; ++mt) {
#pragma unroll
    for (int r = 0; r < 4; ++r) {
      const int gm = bm + wm + mt * 16 + quad * 4 + r;
      const float scv = sc[gm];
      const float c0v = c0f[gm];
      float sq = 0.f;
#pragma unroll
      for (int nt = 0; nt < 4; ++nt) {
        const int gn = bn + wn + nt * 16 + m16;
        float v = scv * (acc[mt][nt][r] - c0v * wc0[gn]) + bias[gn];
        Cb[(size_t)gm * N + gn] = f2bf(v);
        sq += (gn == 0) ? 0.f : v * v;
      }
      sq += __shfl_xor(sq, 1, 64);
      sq += __shfl_xor(sq, 2, 64);
      sq += __shfl_xor(sq, 4, 64);
      sq += __shfl_xor(sq, 8, 64);
      if (m16 == 0) part[(size_t)gm * NBLK + 2 * bxi + (wave & 1)] = sq;
    }
  }
}

// ---------------- 256x256 deep-pipelined NT GEMM, single-barrier iteration ----------------
// 512 threads = 8 waves (2M x 4N); per-wave 128x64 output, acc[8][4].
// LDS: 4-slot ring of (A 256x32 + B 256x32) bf16 = 4 x 32KB = 128KB.
// Tile t computes from slot t&3; tile t+3 staged into slot (t+3)&3 (dead since t-1).
// R4 change: ONE barrier per iteration. Iter body = {4 GLL issue; 12 ds_read_b128;
//   32 MFMA (setprio); vmcnt(8); s_barrier}. The removed mid-iter barriers protected
//   nothing (reads hit slot t&3, GLL writes hit (t+3)&3 -- disjoint); they only
//   enforced region-lockstep, serializing the LDS pipe (1156 cyc/iter/CU) with the
//   matrix pipe (1242 cyc/iter/CU) -- measured 2453 cyc/iter = the sum, MfmaUtil 47%.
//   Now the compiler's fine lgkmcnt(N) overlaps MFMA with in-flight ds_reads within
//   a wave, and the 2 waves/SIMD drift within the iteration across pipes.
// Correctness chain (unchanged): per-iter `asm vmcnt(8) ::: "memory"` + s_barrier:
//   - residency: at end of iter t, outstanding <=8 VMEM = GLLs of iters t-1,t
//     (tiles t+2,t+3) -> tiles <= t+1 resident; barrier makes it workgroup-wide.
//   - WAR: iter-t GLLs (slot (t-1)&3) issue only after the end-of-iter-(t-1) barrier,
//     by which point every wave's slot-(t-1)&3 reads have landed in registers
//     (each ds_read has a dependent MFMA issued before that barrier).
//   - the asm memory clobber + barrier also fence compiler reordering across iters.
// Granule swizzle (measured 0 conflicts): LDS granule g of row r = global g ^ ((r>>1)&3).
// Epilogue: y = sc[m]*(acc - c0f[m]*wc0[n]) + bias[n]; partials part[gm*64 + bxi*4 + wc].
template<int N, int K>
__global__ __launch_bounds__(512, 2) void k_gemm256(
    const unsigned short* __restrict__ A,
    const unsigned short* __restrict__ B,
    const float* __restrict__ bias,
    const float* __restrict__ sc,
    const float* __restrict__ c0f,
    const float* __restrict__ wc0,
    unsigned short* __restrict__ Cb,
    float* __restrict__ part)
{
  static_assert(K % 32 == 0 && K / 32 >= 4, "need >=4 K-tiles");
  constexpr int NT = K / 32;
  __shared__ __align__(16) unsigned short S[4][2][8192];   // [slot][A/B][256*32]

  const int tid  = threadIdx.x;
  const int wave = tid >> 6;
  const int lane = tid & 63;
  const int quad = lane >> 4;
  const int m16  = lane & 15;
  const int wr   = wave >> 2;     // 0..1 (M)
  const int wc   = wave & 3;      // 0..3 (N)

  // bijective XCD swizzle: 512 blocks = 8 XCDs x 64; each XCD gets an 8x8 tile patch
  const int j = blockIdx.x & 7;
  const int k = blockIdx.x >> 3;                 // 0..63
  const int bxi = 8 * (j & 1) + (k & 7);         // 0..15  (N/256)
  const int byi = 8 * (j >> 1) + (k >> 3);       // 0..31  (M/256)
  const int bm = byi * 256;
  const int bn = bxi * 256;

  // staging: thread -> row tid>>2 (0..127), LDS granule tid&3; global granule pre-swizzled
  const int gsw8 = (((tid & 3) ^ ((tid >> 3) & 3)) << 3);
  const unsigned short* gA = A + (size_t)(bm + (tid >> 2)) * K + gsw8;
  const unsigned short* gB = B + (size_t)(bn + (tid >> 2)) * K + gsw8;
  const int ld0 = wave * 512;          // rows  wave*16 .. +15
  const int ld1 = 4096 + wave * 512;   // rows 128+wave*16 .. +15

  // read-side swizzle + fragment base offsets (elements)
  const int rsw8 = ((quad ^ ((m16 >> 1) & 3)) << 3);
  const int aoff = (wr * 128 + m16) * 32 + rsw8;
  const int boff = (wc * 64  + m16) * 32 + rsw8;

  floatx4 acc[8][4];
#pragma unroll
  for (int i = 0; i < 8; ++i)
#pragma unroll
    for (int jj = 0; jj < 4; ++jj)
#pragma unroll
      for (int r = 0; r < 4; ++r) acc[i][jj][r] = 0.0f;

#define GLL(SRC, DST) __builtin_amdgcn_global_load_lds((gbl_void_t*)(void*)(SRC), (lds_void_t*)(DST), 16, 0, 0)

  // prologue: stage tiles 0,1,2 (12 loads/thread); wait all but newest 8 -> tile 0 resident
#pragma unroll
  for (int tt = 0; tt < 3; ++tt) {
    const unsigned short* pa = gA + tt * 32;
    const unsigned short* pb = gB + tt * 32;
    GLL(pa,                   &S[tt][0][ld0]);
    GLL(pa + (size_t)128 * K, &S[tt][0][ld1]);
    GLL(pb,                   &S[tt][1][ld0]);
    GLL(pb + (size_t)128 * K, &S[tt][1][ld1]);
  }
  asm volatile("s_waitcnt vmcnt(8)" ::: "memory");
  __builtin_amdgcn_s_barrier();

  for (int t = 0; t < NT; ++t) {
    const int slot = t & 3;
    const int s3   = (t + 3) & 3;
    const unsigned short* Asl = &S[slot][0][0];
    const unsigned short* Bsl = &S[slot][1][0];
    // tail: clamp source tile (re-stages last tile into a dead slot; keeps vmcnt uniform)
    const int kt = ((t + 3 < NT) ? (t + 3) : (NT - 1)) * 32;
    const unsigned short* ga = gA + kt;
    const unsigned short* gb = gB + kt;

    // stage tile t+3 (issue early; HBM latency hides under this iter's compute)
    GLL(ga,                   &S[s3][0][ld0]);
    GLL(ga + (size_t)128 * K, &S[s3][0][ld1]);
    GLL(gb,                   &S[s3][1][ld0]);
    GLL(gb + (size_t)128 * K, &S[s3][1][ld1]);

    // fragment reads: 12 x ds_read_b128 (a 0..7 via a[], a2[]; b 0..3 shared)
    bf16x8 a[4], b[4], a2[4];
#pragma unroll
    for (int f = 0; f < 4; ++f) a[f]  = *(const bf16x8*)(Asl + aoff + f * 512);
#pragma unroll
    for (int n = 0; n < 4; ++n) b[n]  = *(const bf16x8*)(Bsl + boff + n * 512);
#pragma unroll
    for (int f = 0; f < 4; ++f) a2[f] = *(const bf16x8*)(Asl + aoff + 2048 + f * 512);

    // 32 MFMA; compiler inserts fine-grained lgkmcnt(N) so early MFMAs overlap late reads
    __builtin_amdgcn_s_setprio(1);
#pragma unroll
    for (int f = 0; f < 4; ++f)
#pragma unroll
      for (int n = 0; n < 4; ++n)
        acc[f][n] = __builtin_amdgcn_mfma_f32_16x16x32_bf16(a[f], b[n], acc[f][n], 0, 0, 0);
#pragma unroll
    for (int f = 0; f < 4; ++f)
#pragma unroll
      for (int n = 0; n < 4; ++n)
        acc[f + 4][n] = __builtin_amdgcn_mfma_f32_16x16x32_bf16(a2[f], b[n], acc[f + 4][n], 0, 0, 0);
    __builtin_amdgcn_s_setprio(0);

    // counted wait: tiles <= t+1 resident; tiles t+2,t+3 (8 loads) stay in flight.
    // This inline asm (memory clobber) + barrier is the per-iteration fence.
    asm volatile("s_waitcnt vmcnt(8)" ::: "memory");
    __builtin_amdgcn_s_barrier();
  }
#undef GLL

  // drain outstanding global_load_lds before waves can retire (LDS is freed at endpgm)
  asm volatile("s_waitcnt vmcnt(0)" ::: "memory");

  // epilogue: C/D layout col = lane&15, row = quad*4 + r
  const int wm = wr * 128;
  const int wn = wc * 64;
#pragma unroll
  for (int mt = 0; mt < 8; ++mt) {
#pragma unroll
    for (int r = 0; r < 4; ++r) {
      const int gm = bm + wm + mt * 16 + quad * 4 + r;
      const float scv = sc[gm];
      const float c0v = c0f[gm];
      float sq = 0.f;
#pragma unroll
      for (int nt = 0; nt < 4; ++nt) {
        const int gn = bn + wn + nt * 16 + m16;
        float v = scv * (acc[mt][nt][r] - c0v * wc0[gn]) + bias[gn];
        Cb[(size_t)gm * N + gn] = f2bf(v);
        sq += (gn == 0) ? 0.f : v * v;
      }
      sq += __shfl_xor(sq, 1, 64);
      sq += __shfl_xor(sq, 2, 64);
      sq += __shfl_xor(sq, 4, 64);
      sq += __shfl_xor(sq, 8, 64);
      if (m16 == 0) part[(size_t)gm * 64 + bxi * 4 + wc] = sq;
    }
  }
}

extern "C" void kernel_launch(void* const* d_in, const int* in_sizes, int n_in,
                              void* d_out, int out_size, void* d_ws, size_t ws_size,
                              hipStream_t stream) {
  const void* x  = d_in[0];
  const void* W1 = d_in[1];
  const void* b1 = d_in[2];
  const void* W2 = d_in[3];
  const void* b2 = d_in[4];
  const void* W3 = d_in[5];
  const void* b3 = d_in[6];

  const int NR = 8192, DIN = 1024, DH = 4096, DOUT = 1024;

  char* ws = (char*)d_ws;
  size_t off = 0;
  int* mode = (int*)(ws + off);                        off += 256;
  unsigned short* W1b = (unsigned short*)(ws + off);   off += (size_t)DH * DIN * 2;
  unsigned short* W2b = (unsigned short*)(ws + off);   off += (size_t)DH * DH * 2;
  unsigned short* W3b = (unsigned short*)(ws + off);   off += (size_t)DOUT * DH * 2;
  unsigned short* xb  = (unsigned short*)(ws + off);   off += (size_t)NR * DIN * 2;
  unsigned short* y1  = (unsigned short*)(ws + off);   off += (size_t)NR * DH * 2;
  unsigned short* y2  = (unsigned short*)(ws + off);   off += (size_t)NR * DH * 2;
  unsigned short* y3  = (unsigned short*)(ws + off);   off += (size_t)NR * DOUT * 2;
  float* part1 = (float*)(ws + off);                   off += (size_t)NR * 64 * 4;
  float* part2 = (float*)(ws + off);                   off += (size_t)NR * 64 * 4;
  float* part3 = (float*)(ws + off);                   off += (size_t)NR * 16 * 4;
  float* sc0  = (float*)(ws + off);                    off += (size_t)NR * 4;
  float* x0c  = (float*)(ws + off);                    off += (size_t)NR * 4;
  float* sc1  = (float*)(ws + off);                    off += (size_t)NR * 4;
  float* c01  = (float*)(ws + off);                    off += (size_t)NR * 4;
  float* sc2  = (float*)(ws + off);                    off += (size_t)NR * 4;
  float* c02  = (float*)(ws + off);                    off += (size_t)NR * 4;
  float* ss3  = (float*)(ws + off);                    off += (size_t)NR * 4;
  float* w1c0 = (float*)(ws + off);                    off += (size_t)DH * 4;
  float* w2c0 = (float*)(ws + off);                    off += (size_t)DH * 4;
  float* w3c0 = (float*)(ws + off);                    off += (size_t)DOUT * 4;
  float* b1f  = (float*)(ws + off);                    off += (size_t)DH * 4;
  float* b2f  = (float*)(ws + off);                    off += (size_t)DH * 4;
  float* b3f  = (float*)(ws + off);                    off += (size_t)DOUT * 4;

  k_init<<<16, 256, 0, stream>>>((const unsigned short*)x, mode, b1, b2, b3, b1f, b2f, b3f);

  k_cvtw<128><<<(DH * DIN / 8 + 255) / 256, 256, 0, stream>>>(W1, W1b, mode, DH * DIN / 8, w1c0);
  k_cvtw<512><<<(DH * DH  / 8 + 255) / 256, 256, 0, stream>>>(W2, W2b, mode, DH * DH / 8, w2c0);
  k_cvtw<512><<<(DOUT * DH / 8 + 255) / 256, 256, 0, stream>>>(W3, W3b, mode, DOUT * DH / 8, w3c0);

  k_prep<<<NR, 256, 0, stream>>>(x, xb, sc0, x0c, mode);

  k_gemm256<4096, 1024><<<512, 512, 0, stream>>>(
      xb, W1b, b1f, sc0, x0c, w1c0, y1, part1);
  k_sc<64><<<(NR + 255) / 256, 256, 0, stream>>>(part1, y1, DH, sc1, c01, nullptr, NR);

  k_gemm256<4096, 4096><<<512, 512, 0, stream>>>(
      y1, W2b, b2f, sc1, c01, w2c0, y2, part2);
  k_sc<64><<<(NR + 255) / 256, 256, 0, stream>>>(part2, y2, DH, sc2, c02, nullptr, NR);

  k_gemm_bt<1024, 4096, 16, 8><<<512, 256, 0, stream>>>(
      y2, W3b, b3f, sc2, c02, w3c0, y3, part3);
  k_sc<16><<<(NR + 255) / 256, 256, 0, stream>>>(part3, y3, DOUT, sc0, x0c, ss3, NR);

  k_final<<<NR, 256, 0, stream>>>(y3, ss3, d_out, mode);
}